// Round 17
// baseline (496.790 us; speedup 1.0000x reference)
//
#include <hip/hip_runtime.h>
#include <hip/hip_bf16.h>
#include <math.h>

#define N_NODES 50000
#define N_EDGES 800000
#define D_IN 256
#define D_HID 256
#define D_OUT 128

typedef unsigned short ushort_t;
typedef unsigned char uchar_t;
typedef __attribute__((ext_vector_type(8))) short bf16x8;
typedef __attribute__((ext_vector_type(4))) float f32x4;

__device__ inline ushort_t f2bf(float f) {
    __hip_bfloat16 h = __float2bfloat16(f);  // RNE
    return *reinterpret_cast<ushort_t*>(&h);
}
// fp8 e4m3 encode (RNE, HW): one value -> low byte
__device__ inline uchar_t f2fp8(float a) {
    int w = __builtin_amdgcn_cvt_pk_fp8_f32(a, a, 0, false);
    return (uchar_t)(w & 0xff);
}
// fp8 e4m3 decode: 4 bytes -> 4 floats (GCC-vector result: index, not .x/.y)
__device__ inline void fp8x4_to_f32(unsigned u, float* o) {
    auto p0 = __builtin_amdgcn_cvt_pk_f32_fp8(u, false);
    auto p1 = __builtin_amdgcn_cvt_pk_f32_fp8(u, true);
    o[0] = p0[0]; o[1] = p0[1]; o[2] = p1[0]; o[3] = p1[1];
}
// fp8 e4m3 decode: 2 bytes (low word) -> 2 floats
__device__ inline void fp8x2_to_f32(unsigned u, float* o) {
    auto p0 = __builtin_amdgcn_cvt_pk_f32_fp8(u, false);
    o[0] = p0[0]; o[1] = p0[1];
}

#define NODES_PER_GRP 6250   // count grouping: 8 * 6250 = 50000
#define FILL_GROUPS 64
#define FILL_NPG 782         // 64 * 782 = 50048 >= 50000

// ================= fused: RANGED degree count + weight convert + zero rows =================

__global__ __launch_bounds__(256) void k_count_convW(const int* __restrict__ dst,
                                                     int* __restrict__ degI,
                                                     const float* __restrict__ W1,
                                                     const float* __restrict__ W2,
                                                     ushort_t* __restrict__ Wt1,
                                                     ushort_t* __restrict__ Wt2,
                                                     uchar_t* __restrict__ h1z,
                                                     uchar_t* __restrict__ h2z) {
    const int b = blockIdx.x;
    if (b < 512) {
        const int g = b & 7;
        const int slice = b >> 3;            // 0..63
        const int lo = g * NODES_PER_GRP, hi = lo + NODES_PER_GRP;
        const int i0 = slice * 12500;        // 64*12500 = 800000
        for (int i = i0 + threadIdx.x; i < i0 + 12500; i += 256) {
            const int d = dst[i];
            if (d >= lo && d < hi) atomicAdd(&degI[d], 1);
        }
    } else {
        int i = (b - 512) * 256 + threadIdx.x;
        const int n1 = D_IN * D_HID;       // 65536
        const int n2 = D_HID * D_OUT;      // 32768
        if (i < n1) {
            int k = i / D_HID, n = i % D_HID;
            Wt1[(size_t)n * D_IN + k] = f2bf(W1[i]);
        } else if (i < n1 + n2) {
            int j = i - n1;
            int k = j / D_OUT, n = j % D_OUT;
            Wt2[(size_t)n * D_HID + k] = f2bf(W2[j]);
        } else {
            int j = i - n1 - n2;
            if (j < D_HID) h1z[j] = 0;
            else if (j < D_HID + D_OUT) h2z[j - D_HID] = 0;
        }
    }
}

// ================= self-sufficient scan over PADDED degrees (pad to 16) =================

__global__ __launch_bounds__(256) void k_scan_apply(const int* __restrict__ degI,
                                                    int* __restrict__ offs,
                                                    float* __restrict__ dinv,
                                                    ushort_t* __restrict__ ebuf, int n) {
    __shared__ int s[256];
    const int t = threadIdx.x;
    const int b = blockIdx.x;

    int pre = 0;
    const int lim = b * 256;
    for (int i = t; i < lim; i += 256) pre += (degI[i] + 15) & ~15;
    s[t] = pre;
    __syncthreads();
    for (int st = 128; st > 0; st >>= 1) {
        if (t < st) s[t] += s[t + st];
        __syncthreads();
    }
    const int blockoff = s[0];
    __syncthreads();

    const int i = b * 256 + t;
    const int deg = (i < n) ? degI[i] : 0;
    const int v = (deg + 15) & ~15;
    s[t] = v;
    __syncthreads();
    for (int off = 1; off < 256; off <<= 1) {
        int u = 0;
        if (t >= off) u = s[t - off];
        __syncthreads();
        if (t >= off) s[t] += u;
        __syncthreads();
    }
    const int excl = s[t] - v + blockoff;
    if (i < n) {
        offs[i] = excl;
        dinv[i] = rsqrtf((float)(1 + deg));
        for (int p = excl + deg; p < excl + v; ++p) ebuf[p] = (ushort_t)N_NODES;
        if (i == n - 1) offs[n] = excl + v;
    }
}

// ================= fused: LDS-cursor bucket fill + GEMM1 =================
// blocks [0, gemmBlocks): GEMM1 128x256 tile, 512 threads (8 waves), BK=32
//   h1[M,256](fp8) = (x[M,256](f32) @ Wt1^T) * dinv[row]
// blocks [gemmBlocks, +64): fill — block g owns nodes [g*782,(g+1)*782).
//   Cursors live in LDS (init from offs); the whole dst stream is swept as
//   int4 (L2-resident per XCD); in-range edges insert via LDS atomic + one
//   ushort store into the group's ~25KB ebuf region (single-CU ownership ->
//   each dirty line written back ~once; zero global atomics).

__global__ __launch_bounds__(512) void k_fill_gemm1(const int* __restrict__ src,
                                                    const int* __restrict__ dst,
                                                    const int* __restrict__ offs,
                                                    ushort_t* __restrict__ ebuf,
                                                    const float* __restrict__ A,
                                                    const ushort_t* __restrict__ Bt,
                                                    const float* __restrict__ dinvD,
                                                    uchar_t* __restrict__ C,
                                                    int M, int gemmBlocks) {
    __shared__ ushort_t As[128 * 40];
    __shared__ ushort_t Bs[256 * 40];

    if (blockIdx.x >= gemmBlocks) {
        // ---- LDS-cursor fill ----
        const int g = blockIdx.x - gemmBlocks;      // 0..63
        const int lo = g * FILL_NPG;
        const int hi = min(lo + FILL_NPG, M);
        const int npg = hi - lo;
        int* lcur = (int*)As;                       // 782 ints = 3.1KB (reuse As)
        for (int j = threadIdx.x; j < npg; j += 512)
            lcur[j] = offs[lo + j];
        __syncthreads();

        const int4* d4 = (const int4*)dst;
        for (int ii = threadIdx.x; ii < N_EDGES / 4; ii += 512) {
            const int4 dv = d4[ii];
            const int bi = ii * 4;
#pragma unroll
            for (int k = 0; k < 4; ++k) {
                const int d = (&dv.x)[k];
                if (d >= lo && d < hi) {
                    const int pos = atomicAdd(&lcur[d - lo], 1);
                    ebuf[pos] = (ushort_t)src[bi + k];
                }
            }
        }
        return;
    }

    // ---- GEMM1: h1 = fp8((x @ Wt1^T) * dinv[row]) ----
    const int t = threadIdx.x;
    const int lane = t & 63;
    const int w = t >> 6;
    const int wr = w >> 2;
    const int wc = w & 3;
    const int m0 = blockIdx.x * 128;

    const int arow = t >> 2;
    const int acol = (t & 3) * 8;
    const int brow = t >> 1;
    const int bcol = (t & 1) * 16;

    f32x4 acc[4][4];
#pragma unroll
    for (int m = 0; m < 4; ++m)
#pragma unroll
        for (int n = 0; n < 4; ++n)
#pragma unroll
            for (int i = 0; i < 4; ++i) acc[m][n][i] = 0.0f;

    for (int kt = 0; kt < 256; kt += 32) {
        {
            const int gr = m0 + arow;
            float4 v0 = make_float4(0.f, 0.f, 0.f, 0.f);
            float4 v1 = make_float4(0.f, 0.f, 0.f, 0.f);
            if (gr < M) {
                const float* p = A + (size_t)gr * 256 + kt + acol;
                v0 = *(const float4*)p;
                v1 = *(const float4*)(p + 4);
            }
            ushort4 u0, u1;
            u0.x = f2bf(v0.x); u0.y = f2bf(v0.y); u0.z = f2bf(v0.z); u0.w = f2bf(v0.w);
            u1.x = f2bf(v1.x); u1.y = f2bf(v1.y); u1.z = f2bf(v1.z); u1.w = f2bf(v1.w);
            *(ushort4*)&As[arow * 40 + acol] = u0;
            *(ushort4*)&As[arow * 40 + acol + 4] = u1;
        }
        {
            const uint4* p = (const uint4*)(Bt + (size_t)brow * 256 + kt + bcol);
            uint4 v0 = p[0], v1 = p[1];
            *(uint4*)&Bs[brow * 40 + bcol] = v0;
            *(uint4*)&Bs[brow * 40 + bcol + 8] = v1;
        }
        __syncthreads();

        const int kg = (lane >> 4) * 8;
        const int lr = lane & 15;
        bf16x8 a[4], b[4];
#pragma unroll
        for (int m = 0; m < 4; ++m)
            a[m] = *(const bf16x8*)&As[(wr * 64 + m * 16 + lr) * 40 + kg];
#pragma unroll
        for (int n = 0; n < 4; ++n)
            b[n] = *(const bf16x8*)&Bs[(wc * 64 + n * 16 + lr) * 40 + kg];
#pragma unroll
        for (int m = 0; m < 4; ++m)
#pragma unroll
            for (int n = 0; n < 4; ++n)
                acc[m][n] = __builtin_amdgcn_mfma_f32_16x16x32_bf16(a[m], b[n], acc[m][n], 0, 0, 0);
        __syncthreads();
    }

    const int lr = lane & 15;
    const int rg = (lane >> 4) * 4;
#pragma unroll
    for (int m = 0; m < 4; ++m) {
        const int rb = m0 + wr * 64 + m * 16 + rg;
#pragma unroll
        for (int i = 0; i < 4; ++i) {
            const int row = rb + i;
            if (row < M) {
                const float dr = dinvD[row];
#pragma unroll
                for (int n = 0; n < 4; ++n) {
                    const int col = wc * 64 + n * 16 + lr;
                    C[(size_t)row * 256 + col] = f2fp8(acc[m][n][i] * dr);
                }
            }
        }
    }
}

// ================= shared: 16 scalarized ushort indices (32B, 16B-aligned) =================

__device__ inline void ld_idx16u(const ushort_t* __restrict__ p, int* s) {
    uint4 a = ((const uint4*)p)[0];
    uint4 b = ((const uint4*)p)[1];
    unsigned w0 = __builtin_amdgcn_readfirstlane(a.x);
    unsigned w1 = __builtin_amdgcn_readfirstlane(a.y);
    unsigned w2 = __builtin_amdgcn_readfirstlane(a.z);
    unsigned w3 = __builtin_amdgcn_readfirstlane(a.w);
    unsigned w4 = __builtin_amdgcn_readfirstlane(b.x);
    unsigned w5 = __builtin_amdgcn_readfirstlane(b.y);
    unsigned w6 = __builtin_amdgcn_readfirstlane(b.z);
    unsigned w7 = __builtin_amdgcn_readfirstlane(b.w);
    s[0]  = w0 & 0xffff; s[1]  = w0 >> 16;
    s[2]  = w1 & 0xffff; s[3]  = w1 >> 16;
    s[4]  = w2 & 0xffff; s[5]  = w2 >> 16;
    s[6]  = w3 & 0xffff; s[7]  = w3 >> 16;
    s[8]  = w4 & 0xffff; s[9]  = w4 >> 16;
    s[10] = w5 & 0xffff; s[11] = w5 >> 16;
    s[12] = w6 & 0xffff; s[13] = w6 >> 16;
    s[14] = w7 & 0xffff; s[15] = w7 >> 16;
}

// ================= FUSED: gather1 (fp8 CSR) + GEMM2 — 8-wave version =================

__global__ __launch_bounds__(512) void k_agg_gemm2(const uchar_t* __restrict__ h,
                                                   const float* __restrict__ dinv,
                                                   const int* __restrict__ offs,
                                                   const ushort_t* __restrict__ ebuf,
                                                   const float* __restrict__ bias,
                                                   const ushort_t* __restrict__ Bt,
                                                   uchar_t* __restrict__ h2, int n) {
    __shared__ ushort_t As[64 * 264];   // 64 rows x 256 (+8 pad) bf16 agg tile
    __shared__ ushort_t Bs[128 * 40];   // Wt2 K-tile

    const int t = threadIdx.x;
    const int lane = t & 63;
    const int w = t >> 6;               // 0..7
    const int m0 = blockIdx.x * 64;

    // ---- phase 1: gather 8 nodes per wave ----
    const int base = lane * 4;
    const uchar_t* hb = h + base;

    for (int i = 0; i < 8; ++i) {
        const int row = w * 8 + i;
        const int node = m0 + row;
        if (node < n) {
            float acc[4];
            {
                const unsigned u = *(const unsigned*)(hb + (size_t)node * D_HID);
                fp8x4_to_f32(u, acc);
            }
            int e = __builtin_amdgcn_readfirstlane(offs[node]);
            const int e1 = __builtin_amdgcn_readfirstlane(offs[node + 1]);
            int cs[16], ns[16];
            bool have = e < e1;
            if (have) ld_idx16u(ebuf + e, cs);
            while (have) {
                const int en = e + 16;
                const bool hn = en < e1;
                unsigned u[16];
#pragma unroll
                for (int j = 0; j < 16; ++j)
                    u[j] = *(const unsigned*)(hb + (size_t)cs[j] * D_HID);
                if (hn) ld_idx16u(ebuf + en, ns);
#pragma unroll
                for (int j = 0; j < 16; ++j) {
                    float d[4];
                    fp8x4_to_f32(u[j], d);
                    acc[0] += d[0]; acc[1] += d[1]; acc[2] += d[2]; acc[3] += d[3];
                }
                e = en; have = hn;
#pragma unroll
                for (int j = 0; j < 16; ++j) cs[j] = ns[j];
            }
            const float di = dinv[node];
            ushort4 o;
            o.x = f2bf(fmaxf(di * acc[0] + bias[base + 0], 0.f));
            o.y = f2bf(fmaxf(di * acc[1] + bias[base + 1], 0.f));
            o.z = f2bf(fmaxf(di * acc[2] + bias[base + 2], 0.f));
            o.w = f2bf(fmaxf(di * acc[3] + bias[base + 3], 0.f));
            *(ushort4*)&As[row * 264 + base] = o;
        }
    }
    __syncthreads();

    // ---- phase 2: 64x128 GEMM vs Wt2; wave w owns cols [w*16, w*16+16) ----
    const int lr = lane & 15;
    const int kg = (lane >> 4) * 8;

    f32x4 acc2[4];
#pragma unroll
    for (int m = 0; m < 4; ++m)
#pragma unroll
        for (int i = 0; i < 4; ++i) acc2[m][i] = 0.0f;

    for (int kt = 0; kt < 256; kt += 32) {
        {
            const int srow = t >> 2;          // 0..127
            const int scol = (t & 3) * 8;     // 0,8,16,24
            const uint4* p = (const uint4*)(Bt + (size_t)srow * 256 + kt + scol);
            *(uint4*)&Bs[srow * 40 + scol] = p[0];
        }
        __syncthreads();

        bf16x8 a[4], b;
#pragma unroll
        for (int m = 0; m < 4; ++m)
            a[m] = *(const bf16x8*)&As[(m * 16 + lr) * 264 + kt + kg];
        b = *(const bf16x8*)&Bs[(w * 16 + lr) * 40 + kg];
#pragma unroll
        for (int m = 0; m < 4; ++m)
            acc2[m] = __builtin_amdgcn_mfma_f32_16x16x32_bf16(a[m], b, acc2[m], 0, 0, 0);
        __syncthreads();
    }

    // epilogue: C/D layout col=lane&15, row=(lane>>4)*4+i ; h2 fp8
    const int rg = (lane >> 4) * 4;
#pragma unroll
    for (int m = 0; m < 4; ++m) {
#pragma unroll
        for (int i = 0; i < 4; ++i) {
            const int gr = m0 + m * 16 + rg + i;
            if (gr < n) {
                const int col = w * 16 + lr;
                h2[(size_t)gr * 128 + col] = f2fp8(acc2[m][i] * dinv[gr]);
            }
        }
    }
}

// ================= gather2: fp8 h2 (128d) -> f32 out (sigmoid+bias) =================

__global__ __launch_bounds__(256) void k_gather_fp8_2(const uchar_t* __restrict__ h,
                                                      const float* __restrict__ dinv,
                                                      const int* __restrict__ offs,
                                                      const ushort_t* __restrict__ ebuf,
                                                      const float* __restrict__ bias,
                                                      float* __restrict__ out, int n) {
    const int node = (blockIdx.x * 256 + threadIdx.x) >> 6;
    const int lane = threadIdx.x & 63;
    if (node >= n) return;

    const int base = lane * 2;
    const uchar_t* hb = h + base;
    const float di = dinv[node];

    float acc[2];
    {
        const unsigned u = *(const ushort_t*)(hb + (size_t)node * D_OUT);
        fp8x2_to_f32(u, acc);
    }

    int e = __builtin_amdgcn_readfirstlane(offs[node]);
    const int e1 = __builtin_amdgcn_readfirstlane(offs[node + 1]);

    int cs[16], ns[16];
    bool have = e < e1;
    if (have) ld_idx16u(ebuf + e, cs);

    while (have) {
        const int en = e + 16;
        const bool hn = en < e1;
        unsigned u[16];
#pragma unroll
        for (int j = 0; j < 16; ++j)
            u[j] = *(const ushort_t*)(hb + (size_t)cs[j] * D_OUT);
        if (hn) ld_idx16u(ebuf + en, ns);
#pragma unroll
        for (int j = 0; j < 16; ++j) {
            float d[2];
            fp8x2_to_f32(u[j], d);
            acc[0] += d[0]; acc[1] += d[1];
        }
        e = en; have = hn;
#pragma unroll
        for (int j = 0; j < 16; ++j) cs[j] = ns[j];
    }

    const float v0 = di * acc[0] + bias[base + 0];
    const float v1 = di * acc[1] + bias[base + 1];
    float2 r;
    r.x = 1.0f / (1.0f + expf(-v0));
    r.y = 1.0f / (1.0f + expf(-v1));
    *(float2*)(out + (size_t)node * D_OUT + base) = r;
}

// ================= launch =================

extern "C" void kernel_launch(void* const* d_in, const int* in_sizes, int n_in,
                              void* d_out, int out_size, void* d_ws, size_t ws_size,
                              hipStream_t stream) {
    const float* x  = (const float*)d_in[0];
    const int*   ei = (const int*)d_in[1];
    const float* W1 = (const float*)d_in[2];
    const float* b1 = (const float*)d_in[3];
    const float* W2 = (const float*)d_in[4];
    const float* b2 = (const float*)d_in[5];
    float* out = (float*)d_out;

    float* wsf    = (float*)d_ws;
    float* dinv   = wsf;                            // [50048] f32
    int*   degI   = (int*)(wsf + 50048);            // [50048]
    int*   offs   = degI + 50048;                   // [50064] (uses 50001)
    int*   cursor = offs + 50064;                   // [50048] (unused; layout keep)
    ushort_t* ebuf= (ushort_t*)(cursor + 50048);    // [1600000] ushort padded CSR, 16B-aligned
    ushort_t* Wt1 = ebuf + 1600000;                 // [65536] bf16
    ushort_t* Wt2 = Wt1 + 65536;                    // [32768] bf16
    uchar_t*  h1  = (uchar_t*)(Wt2 + 32768);        // [50048*256] fp8, row 50000 = zeros
    uchar_t*  h2  = h1 + (size_t)50048 * D_HID;     // [50048*128] fp8, row 50000 = zeros

    const int* src = ei;
    const int* dst = ei + N_EDGES;

    const int blocksN = (N_NODES + 255) / 256;  // 196

    // 1) zero degree counters
    hipMemsetAsync(degI, 0, N_NODES * sizeof(int), stream);

    // 2) fused: ranged degree count (512 blocks) + weight convert/zero rows (386)
    k_count_convW<<<512 + 386, 256, 0, stream>>>(dst, degI, W1, W2, Wt1, Wt2,
                                                 h1 + (size_t)N_NODES * D_HID,
                                                 h2 + (size_t)N_NODES * D_OUT);

    // 3) self-sufficient scan + dinv + ebuf padding
    k_scan_apply<<<blocksN, 256, 0, stream>>>(degI, offs, dinv, ebuf, N_NODES);

    // 4) fused: LDS-cursor fill (64 blocks) + layer-1 GEMM (overlapped)
    {
        const int gemmBlocks = (N_NODES + 127) / 128;          // 391
        k_fill_gemm1<<<gemmBlocks + FILL_GROUPS, 512, 0, stream>>>(
            src, dst, offs, ebuf, x, Wt1, dinv, h1, N_NODES, gemmBlocks);
    }

    // 5) FUSED: aggregate 256-dim (fp8) + GEMM2 -> h2 fp8 (8 waves, agg1 in LDS)
    k_agg_gemm2<<<(N_NODES + 63) / 64, 512, 0, stream>>>(
        h1, dinv, offs, ebuf, b1, Wt2, h2, N_NODES);

    // 6) aggregate 128-dim (fp8 payload): out = sigmoid(dinv*(sum) + b2)
    k_gather_fp8_2<<<(N_NODES * 64 + 255) / 256, 256, 0, stream>>>(
        h2, dinv, offs, ebuf, b2, out, N_NODES);
}

// Round 18
// 205.731 us; speedup vs baseline: 2.4148x; 2.4148x over previous
//
#include <hip/hip_runtime.h>
#include <hip/hip_bf16.h>
#include <math.h>

#define N_NODES 50000
#define N_EDGES 800000
#define D_IN 256
#define D_HID 256
#define D_OUT 128

typedef unsigned short ushort_t;
typedef unsigned char uchar_t;
typedef __attribute__((ext_vector_type(8))) short bf16x8;
typedef __attribute__((ext_vector_type(4))) float f32x4;

__device__ inline ushort_t f2bf(float f) {
    __hip_bfloat16 h = __float2bfloat16(f);  // RNE
    return *reinterpret_cast<ushort_t*>(&h);
}
// fp8 e4m3 encode (RNE, HW): one value -> low byte
__device__ inline uchar_t f2fp8(float a) {
    int w = __builtin_amdgcn_cvt_pk_fp8_f32(a, a, 0, false);
    return (uchar_t)(w & 0xff);
}
// fp8 e4m3 decode: 4 bytes -> 4 floats (GCC-vector result: index, not .x/.y)
__device__ inline void fp8x4_to_f32(unsigned u, float* o) {
    auto p0 = __builtin_amdgcn_cvt_pk_f32_fp8(u, false);
    auto p1 = __builtin_amdgcn_cvt_pk_f32_fp8(u, true);
    o[0] = p0[0]; o[1] = p0[1]; o[2] = p1[0]; o[3] = p1[1];
}
// fp8 e4m3 decode: 2 bytes (low word) -> 2 floats
__device__ inline void fp8x2_to_f32(unsigned u, float* o) {
    auto p0 = __builtin_amdgcn_cvt_pk_f32_fp8(u, false);
    o[0] = p0[0]; o[1] = p0[1];
}

#define NODES_PER_GRP 6250   // 8 * 6250 = 50000

// ================= fused: RANGED degree count + weight convert + zero rows =================

__global__ __launch_bounds__(256) void k_count_convW(const int* __restrict__ dst,
                                                     int* __restrict__ degI,
                                                     const float* __restrict__ W1,
                                                     const float* __restrict__ W2,
                                                     ushort_t* __restrict__ Wt1,
                                                     ushort_t* __restrict__ Wt2,
                                                     uchar_t* __restrict__ h1z,
                                                     uchar_t* __restrict__ h2z) {
    const int b = blockIdx.x;
    if (b < 512) {
        const int g = b & 7;
        const int slice = b >> 3;            // 0..63
        const int lo = g * NODES_PER_GRP, hi = lo + NODES_PER_GRP;
        const int i0 = slice * 12500;        // 64*12500 = 800000
        for (int i = i0 + threadIdx.x; i < i0 + 12500; i += 256) {
            const int d = dst[i];
            if (d >= lo && d < hi) atomicAdd(&degI[d], 1);
        }
    } else {
        int i = (b - 512) * 256 + threadIdx.x;
        const int n1 = D_IN * D_HID;       // 65536
        const int n2 = D_HID * D_OUT;      // 32768
        if (i < n1) {
            int k = i / D_HID, n = i % D_HID;
            Wt1[(size_t)n * D_IN + k] = f2bf(W1[i]);
        } else if (i < n1 + n2) {
            int j = i - n1;
            int k = j / D_OUT, n = j % D_OUT;
            Wt2[(size_t)n * D_HID + k] = f2bf(W2[j]);
        } else {
            int j = i - n1 - n2;
            if (j < D_HID) h1z[j] = 0;
            else if (j < D_HID + D_OUT) h2z[j - D_HID] = 0;
        }
    }
}

// ================= self-sufficient scan over PADDED degrees (pad to 16) =================

__global__ __launch_bounds__(256) void k_scan_apply(const int* __restrict__ degI,
                                                    int* __restrict__ offs,
                                                    int* __restrict__ cursor,
                                                    float* __restrict__ dinv,
                                                    ushort_t* __restrict__ ebuf, int n) {
    __shared__ int s[256];
    const int t = threadIdx.x;
    const int b = blockIdx.x;

    int pre = 0;
    const int lim = b * 256;
    for (int i = t; i < lim; i += 256) pre += (degI[i] + 15) & ~15;
    s[t] = pre;
    __syncthreads();
    for (int st = 128; st > 0; st >>= 1) {
        if (t < st) s[t] += s[t + st];
        __syncthreads();
    }
    const int blockoff = s[0];
    __syncthreads();

    const int i = b * 256 + t;
    const int deg = (i < n) ? degI[i] : 0;
    const int v = (deg + 15) & ~15;
    s[t] = v;
    __syncthreads();
    for (int off = 1; off < 256; off <<= 1) {
        int u = 0;
        if (t >= off) u = s[t - off];
        __syncthreads();
        if (t >= off) s[t] += u;
        __syncthreads();
    }
    const int excl = s[t] - v + blockoff;
    if (i < n) {
        offs[i] = excl;
        cursor[i] = excl;
        dinv[i] = rsqrtf((float)(1 + deg));
        for (int p = excl + deg; p < excl + v; ++p) ebuf[p] = (ushort_t)N_NODES;
        if (i == n - 1) offs[n] = excl + v;
    }
}

// ================= fused: RANGED bucket fill + GEMM1 =================
// blocks [0, gemmBlocks): GEMM1 128x256 tile, 512 threads (8 waves 2x4), BK=32
//   h1[M,256](fp8) = (x[M,256](f32) @ Wt1^T) * dinv[row]
// blocks [gemmBlocks, +1600): fill — group g=(b-gemmBlocks)&7 owns dst range
//   [g*6250,(g+1)*6250); each group's cursor + ebuf region stays XCD-local
//   under rr dispatch.

__global__ __launch_bounds__(512) void k_fill_gemm1(const int* __restrict__ src,
                                                    const int* __restrict__ dst,
                                                    int* __restrict__ cursor,
                                                    ushort_t* __restrict__ ebuf,
                                                    const float* __restrict__ A,
                                                    const ushort_t* __restrict__ Bt,
                                                    const float* __restrict__ dinvD,
                                                    uchar_t* __restrict__ C,
                                                    int M, int gemmBlocks) {
    __shared__ ushort_t As[128 * 40];
    __shared__ ushort_t Bs[256 * 40];

    if (blockIdx.x >= gemmBlocks) {
        const int fb = blockIdx.x - gemmBlocks;
        const int g = fb & 7;
        const int slice = fb >> 3;            // 0..199
        const int lo = g * NODES_PER_GRP, hi = lo + NODES_PER_GRP;
        const int i0 = slice * 4000;          // 200*4000 = 800000
        for (int i = i0 + threadIdx.x; i < i0 + 4000; i += 512) {
            const int d = dst[i];
            if (d >= lo && d < hi) {
                const int pos = atomicAdd(&cursor[d], 1);
                ebuf[pos] = (ushort_t)src[i];
            }
        }
        return;
    }

    // ---- GEMM1: h1 = fp8((x @ Wt1^T) * dinv[row]) ----
    const int t = threadIdx.x;
    const int lane = t & 63;
    const int w = t >> 6;
    const int wr = w >> 2;
    const int wc = w & 3;
    const int m0 = blockIdx.x * 128;

    const int arow = t >> 2;
    const int acol = (t & 3) * 8;
    const int brow = t >> 1;
    const int bcol = (t & 1) * 16;

    f32x4 acc[4][4];
#pragma unroll
    for (int m = 0; m < 4; ++m)
#pragma unroll
        for (int n = 0; n < 4; ++n)
#pragma unroll
            for (int i = 0; i < 4; ++i) acc[m][n][i] = 0.0f;

    for (int kt = 0; kt < 256; kt += 32) {
        {
            const int gr = m0 + arow;
            float4 v0 = make_float4(0.f, 0.f, 0.f, 0.f);
            float4 v1 = make_float4(0.f, 0.f, 0.f, 0.f);
            if (gr < M) {
                const float* p = A + (size_t)gr * 256 + kt + acol;
                v0 = *(const float4*)p;
                v1 = *(const float4*)(p + 4);
            }
            ushort4 u0, u1;
            u0.x = f2bf(v0.x); u0.y = f2bf(v0.y); u0.z = f2bf(v0.z); u0.w = f2bf(v0.w);
            u1.x = f2bf(v1.x); u1.y = f2bf(v1.y); u1.z = f2bf(v1.z); u1.w = f2bf(v1.w);
            *(ushort4*)&As[arow * 40 + acol] = u0;
            *(ushort4*)&As[arow * 40 + acol + 4] = u1;
        }
        {
            const uint4* p = (const uint4*)(Bt + (size_t)brow * 256 + kt + bcol);
            uint4 v0 = p[0], v1 = p[1];
            *(uint4*)&Bs[brow * 40 + bcol] = v0;
            *(uint4*)&Bs[brow * 40 + bcol + 8] = v1;
        }
        __syncthreads();

        const int kg = (lane >> 4) * 8;
        const int lr = lane & 15;
        bf16x8 a[4], b[4];
#pragma unroll
        for (int m = 0; m < 4; ++m)
            a[m] = *(const bf16x8*)&As[(wr * 64 + m * 16 + lr) * 40 + kg];
#pragma unroll
        for (int n = 0; n < 4; ++n)
            b[n] = *(const bf16x8*)&Bs[(wc * 64 + n * 16 + lr) * 40 + kg];
#pragma unroll
        for (int m = 0; m < 4; ++m)
#pragma unroll
            for (int n = 0; n < 4; ++n)
                acc[m][n] = __builtin_amdgcn_mfma_f32_16x16x32_bf16(a[m], b[n], acc[m][n], 0, 0, 0);
        __syncthreads();
    }

    const int lr = lane & 15;
    const int rg = (lane >> 4) * 4;
#pragma unroll
    for (int m = 0; m < 4; ++m) {
        const int rb = m0 + wr * 64 + m * 16 + rg;
#pragma unroll
        for (int i = 0; i < 4; ++i) {
            const int row = rb + i;
            if (row < M) {
                const float dr = dinvD[row];
#pragma unroll
                for (int n = 0; n < 4; ++n) {
                    const int col = wc * 64 + n * 16 + lr;
                    C[(size_t)row * 256 + col] = f2fp8(acc[m][n][i] * dr);
                }
            }
        }
    }
}

// ================= GEMM2: 128x128 tile, 4 waves, BK=32, A bf16 -> C fp8 =================

__global__ __launch_bounds__(256) void k_gemm2(const ushort_t* __restrict__ A,
                                               const ushort_t* __restrict__ Bt,
                                               const float* __restrict__ dinvD,
                                               uchar_t* __restrict__ C, int M) {
    __shared__ ushort_t As[128 * 40];
    __shared__ ushort_t Bs[128 * 40];

    const int t = threadIdx.x;
    const int lane = t & 63;
    const int w = t >> 6;
    const int wr = w >> 1, wc = w & 1;
    const int m0 = blockIdx.x * 128;

    const int srow = t >> 1;
    const int scol = (t & 1) * 16;

    f32x4 acc[4][4];
#pragma unroll
    for (int m = 0; m < 4; ++m)
#pragma unroll
        for (int n = 0; n < 4; ++n)
#pragma unroll
            for (int i = 0; i < 4; ++i) acc[m][n][i] = 0.0f;

    for (int kt = 0; kt < 256; kt += 32) {
        {
            const int gr = m0 + srow;
            uint4 v0 = make_uint4(0, 0, 0, 0), v1 = make_uint4(0, 0, 0, 0);
            if (gr < M) {
                const uint4* p = (const uint4*)(A + (size_t)gr * 256 + kt + scol);
                v0 = p[0]; v1 = p[1];
            }
            *(uint4*)&As[srow * 40 + scol] = v0;
            *(uint4*)&As[srow * 40 + scol + 8] = v1;
        }
        {
            const uint4* p = (const uint4*)(Bt + (size_t)srow * 256 + kt + scol);
            uint4 v0 = p[0], v1 = p[1];
            *(uint4*)&Bs[srow * 40 + scol] = v0;
            *(uint4*)&Bs[srow * 40 + scol + 8] = v1;
        }
        __syncthreads();

        const int kg = (lane >> 4) * 8;
        const int lr = lane & 15;
        bf16x8 a[4], b[4];
#pragma unroll
        for (int m = 0; m < 4; ++m)
            a[m] = *(const bf16x8*)&As[(wr * 64 + m * 16 + lr) * 40 + kg];
#pragma unroll
        for (int n = 0; n < 4; ++n)
            b[n] = *(const bf16x8*)&Bs[(wc * 64 + n * 16 + lr) * 40 + kg];
#pragma unroll
        for (int m = 0; m < 4; ++m)
#pragma unroll
            for (int n = 0; n < 4; ++n)
                acc[m][n] = __builtin_amdgcn_mfma_f32_16x16x32_bf16(a[m], b[n], acc[m][n], 0, 0, 0);
        __syncthreads();
    }

    const int lr = lane & 15;
    const int rg = (lane >> 4) * 4;
#pragma unroll
    for (int m = 0; m < 4; ++m) {
        const int rb = m0 + wr * 64 + m * 16 + rg;
#pragma unroll
        for (int i = 0; i < 4; ++i) {
            const int row = rb + i;
            if (row < M) {
                const float dr = dinvD[row];
#pragma unroll
                for (int n = 0; n < 4; ++n) {
                    const int col = wc * 64 + n * 16 + lr;
                    C[(size_t)row * 128 + col] = f2fp8(acc[m][n][i] * dr);
                }
            }
        }
    }
}

// ================= shared: 16 scalarized ushort indices (32B, 16B-aligned) =================

__device__ inline void ld_idx16u(const ushort_t* __restrict__ p, int* s) {
    uint4 a = ((const uint4*)p)[0];
    uint4 b = ((const uint4*)p)[1];
    unsigned w0 = __builtin_amdgcn_readfirstlane(a.x);
    unsigned w1 = __builtin_amdgcn_readfirstlane(a.y);
    unsigned w2 = __builtin_amdgcn_readfirstlane(a.z);
    unsigned w3 = __builtin_amdgcn_readfirstlane(a.w);
    unsigned w4 = __builtin_amdgcn_readfirstlane(b.x);
    unsigned w5 = __builtin_amdgcn_readfirstlane(b.y);
    unsigned w6 = __builtin_amdgcn_readfirstlane(b.z);
    unsigned w7 = __builtin_amdgcn_readfirstlane(b.w);
    s[0]  = w0 & 0xffff; s[1]  = w0 >> 16;
    s[2]  = w1 & 0xffff; s[3]  = w1 >> 16;
    s[4]  = w2 & 0xffff; s[5]  = w2 >> 16;
    s[6]  = w3 & 0xffff; s[7]  = w3 >> 16;
    s[8]  = w4 & 0xffff; s[9]  = w4 >> 16;
    s[10] = w5 & 0xffff; s[11] = w5 >> 16;
    s[12] = w6 & 0xffff; s[13] = w6 >> 16;
    s[14] = w7 & 0xffff; s[15] = w7 >> 16;
}

// ================= gather1: fp8 h1 (256d) -> bf16 agg1 (relu+bias) =================

__global__ __launch_bounds__(256) void k_gather_fp8(const uchar_t* __restrict__ h,
                                                    const float* __restrict__ dinv,
                                                    const int* __restrict__ offs,
                                                    const ushort_t* __restrict__ ebuf,
                                                    const float* __restrict__ bias,
                                                    ushort_t* __restrict__ out, int n) {
    const int node = (blockIdx.x * 256 + threadIdx.x) >> 6;
    const int lane = threadIdx.x & 63;
    if (node >= n) return;

    const int base = lane * 4;
    const uchar_t* hb = h + base;
    const float di = dinv[node];

    float acc[4];
    {
        const unsigned u = *(const unsigned*)(hb + (size_t)node * D_HID);
        fp8x4_to_f32(u, acc);
    }

    int e = __builtin_amdgcn_readfirstlane(offs[node]);
    const int e1 = __builtin_amdgcn_readfirstlane(offs[node + 1]);

    int cs[16], ns[16];
    bool have = e < e1;
    if (have) ld_idx16u(ebuf + e, cs);

    while (have) {
        const int en = e + 16;
        const bool hn = en < e1;
        unsigned u[16];
#pragma unroll
        for (int j = 0; j < 16; ++j)
            u[j] = *(const unsigned*)(hb + (size_t)cs[j] * D_HID);
        if (hn) ld_idx16u(ebuf + en, ns);
#pragma unroll
        for (int j = 0; j < 16; ++j) {
            float d[4];
            fp8x4_to_f32(u[j], d);
            acc[0] += d[0]; acc[1] += d[1]; acc[2] += d[2]; acc[3] += d[3];
        }
        e = en; have = hn;
#pragma unroll
        for (int j = 0; j < 16; ++j) cs[j] = ns[j];
    }

    ushort4 o;
    o.x = f2bf(fmaxf(di * acc[0] + bias[base + 0], 0.f));
    o.y = f2bf(fmaxf(di * acc[1] + bias[base + 1], 0.f));
    o.z = f2bf(fmaxf(di * acc[2] + bias[base + 2], 0.f));
    o.w = f2bf(fmaxf(di * acc[3] + bias[base + 3], 0.f));
    *(ushort4*)(out + (size_t)node * D_HID + base) = o;
}

// ================= gather2: fp8 h2 (128d) -> f32 out (sigmoid+bias) =================

__global__ __launch_bounds__(256) void k_gather_fp8_2(const uchar_t* __restrict__ h,
                                                      const float* __restrict__ dinv,
                                                      const int* __restrict__ offs,
                                                      const ushort_t* __restrict__ ebuf,
                                                      const float* __restrict__ bias,
                                                      float* __restrict__ out, int n) {
    const int node = (blockIdx.x * 256 + threadIdx.x) >> 6;
    const int lane = threadIdx.x & 63;
    if (node >= n) return;

    const int base = lane * 2;
    const uchar_t* hb = h + base;
    const float di = dinv[node];

    float acc[2];
    {
        const unsigned u = *(const ushort_t*)(hb + (size_t)node * D_OUT);
        fp8x2_to_f32(u, acc);
    }

    int e = __builtin_amdgcn_readfirstlane(offs[node]);
    const int e1 = __builtin_amdgcn_readfirstlane(offs[node + 1]);

    int cs[16], ns[16];
    bool have = e < e1;
    if (have) ld_idx16u(ebuf + e, cs);

    while (have) {
        const int en = e + 16;
        const bool hn = en < e1;
        unsigned u[16];
#pragma unroll
        for (int j = 0; j < 16; ++j)
            u[j] = *(const ushort_t*)(hb + (size_t)cs[j] * D_OUT);
        if (hn) ld_idx16u(ebuf + en, ns);
#pragma unroll
        for (int j = 0; j < 16; ++j) {
            float d[2];
            fp8x2_to_f32(u[j], d);
            acc[0] += d[0]; acc[1] += d[1];
        }
        e = en; have = hn;
#pragma unroll
        for (int j = 0; j < 16; ++j) cs[j] = ns[j];
    }

    const float v0 = di * acc[0] + bias[base + 0];
    const float v1 = di * acc[1] + bias[base + 1];
    float2 r;
    r.x = 1.0f / (1.0f + expf(-v0));
    r.y = 1.0f / (1.0f + expf(-v1));
    *(float2*)(out + (size_t)node * D_OUT + base) = r;
}

// ================= launch =================

extern "C" void kernel_launch(void* const* d_in, const int* in_sizes, int n_in,
                              void* d_out, int out_size, void* d_ws, size_t ws_size,
                              hipStream_t stream) {
    const float* x  = (const float*)d_in[0];
    const int*   ei = (const int*)d_in[1];
    const float* W1 = (const float*)d_in[2];
    const float* b1 = (const float*)d_in[3];
    const float* W2 = (const float*)d_in[4];
    const float* b2 = (const float*)d_in[5];
    float* out = (float*)d_out;

    float* wsf    = (float*)d_ws;
    float* dinv   = wsf;                            // [50048] f32
    int*   degI   = (int*)(wsf + 50048);            // [50048]
    int*   offs   = degI + 50048;                   // [50064] (uses 50001)
    int*   cursor = offs + 50064;                   // [50048]
    ushort_t* ebuf= (ushort_t*)(cursor + 50048);    // [1600000] ushort padded CSR, 16B-aligned
    ushort_t* Wt1 = ebuf + 1600000;                 // [65536] bf16
    ushort_t* Wt2 = Wt1 + 65536;                    // [32768] bf16
    uchar_t*  h1  = (uchar_t*)(Wt2 + 32768);        // [50048*256] fp8, row 50000 = zeros
    ushort_t* agg1= (ushort_t*)(h1 + (size_t)50048 * D_HID);  // [50048*256] bf16
    uchar_t*  h2  = (uchar_t*)(agg1 + (size_t)50048 * D_HID); // [50048*128] fp8, row 50000 = zeros

    const int* src = ei;
    const int* dst = ei + N_EDGES;

    const int blocksN = (N_NODES + 255) / 256;  // 196

    // 1) zero degree counters
    hipMemsetAsync(degI, 0, N_NODES * sizeof(int), stream);

    // 2) fused: ranged degree count (512 blocks) + weight convert/zero rows (386)
    k_count_convW<<<512 + 386, 256, 0, stream>>>(dst, degI, W1, W2, Wt1, Wt2,
                                                 h1 + (size_t)N_NODES * D_HID,
                                                 h2 + (size_t)N_NODES * D_OUT);

    // 3) self-sufficient scan + dinv + ebuf padding
    k_scan_apply<<<blocksN, 256, 0, stream>>>(degI, offs, cursor, dinv, ebuf, N_NODES);

    // 4) fused: ranged bucket fill (1600 blocks) + layer-1 GEMM (overlapped)
    {
        const int gemmBlocks = (N_NODES + 127) / 128;          // 391
        k_fill_gemm1<<<gemmBlocks + 1600, 512, 0, stream>>>(
            src, dst, cursor, ebuf, x, Wt1, dinv, h1, N_NODES, gemmBlocks);
    }

    // 5) aggregate 256-dim (fp8 payload): agg1 = bf16(relu(dinv*(sum) + b1))
    k_gather_fp8<<<(N_NODES * 64 + 255) / 256, 256, 0, stream>>>(
        h1, dinv, offs, ebuf, b1, agg1, N_NODES);

    // 6) layer 2 GEMM: h2 = fp8((agg1 @ W2) * dinv)
    k_gemm2<<<(N_NODES + 127) / 128, 256, 0, stream>>>(agg1, Wt2, dinv, h2, N_NODES);

    // 7) aggregate 128-dim (fp8 payload): out = sigmoid(dinv*(sum) + b2)
    k_gather_fp8_2<<<(N_NODES * 64 + 255) / 256, 256, 0, stream>>>(
        h2, dinv, offs, ebuf, b2, out, N_NODES);
}